// Round 10
// baseline (263.650 us; speedup 1.0000x reference)
//
#include <hip/hip_runtime.h>
#include <math.h>

#define NH 16
#define DD 128
#define SS 2048
#define NQ 7

typedef __attribute__((ext_vector_type(8))) short bf16x8;
typedef __attribute__((ext_vector_type(16))) float f32x16;

#define MFMA32(a,b,c) __builtin_amdgcn_mfma_f32_32x32x16_bf16(a,b,c,0,0,0)

// manual packed bf16 RNE (HW cvt builtin inflated VGPRs — keep manual)
__device__ __forceinline__ unsigned pkbf(float a, float b){
    unsigned ua = __float_as_uint(a); ua += 0x7FFF + ((ua>>16)&1);
    unsigned ub = __float_as_uint(b); ub += 0x7FFF + ((ub>>16)&1);
    return (ua>>16) | (ub & 0xFFFF0000u);
}

// raw v_exp_f32 (2^x), no libm fixup
__device__ __forceinline__ float fexp2(float x){
#if __has_builtin(__builtin_amdgcn_exp2f)
    return __builtin_amdgcn_exp2f(x);
#else
    return __expf(x * 0.69314718056f);
#endif
}

__device__ __forceinline__ void gl_lds16(const int4* g, int4* l){
    __builtin_amdgcn_global_load_lds((const __attribute__((address_space(1))) void*)g,
                                     (__attribute__((address_space(3))) void*)l, 16, 0, 0);
}

struct cplx { float r, i; };
__device__ __forceinline__ cplx cmul(cplx a, cplx b){ cplx o; o.r = a.r*b.r - a.i*b.i; o.i = a.r*b.i + a.i*b.r; return o; }
__device__ __forceinline__ cplx cadd(cplx a, cplx b){ cplx o; o.r = a.r+b.r; o.i = a.i+b.i; return o; }

// ---------------- gates ----------------
__global__ void gates_kernel(const float* __restrict__ qp, const float* __restrict__ kp,
                             const float* __restrict__ vp, float* __restrict__ gates){
    for (int it = threadIdx.x; it < 3*NH*NQ; it += 256){
        int set = it / (NH*NQ);
        int rem = it % (NH*NQ);
        const float* p = (set==0 ? qp : (set==1 ? kp : vp)) + rem*3;
        float a = p[0]*0.5f, b = p[1]*0.5f, c = p[2]*0.5f;
        float ca=cosf(a), sa=sinf(a), cb=cosf(b), sb=sinf(b), cc=cosf(c), sc=sinf(c);
        cplx rx00={ca,0.f}, rx01={0.f,-sa}, rx10={0.f,-sa}, rx11={ca,0.f};
        cplx ry00={cb,0.f}, ry01={-sb,0.f}, ry10={sb,0.f}, ry11={cb,0.f};
        cplx e0={cc,-sc}, e1={cc,sc};
        cplx m00 = cadd(cmul(ry00,rx00), cmul(ry01,rx10));
        cplx m01 = cadd(cmul(ry00,rx01), cmul(ry01,rx11));
        cplx m10 = cadd(cmul(ry10,rx00), cmul(ry11,rx10));
        cplx m11 = cadd(cmul(ry10,rx01), cmul(ry11,rx11));
        cplx g00 = cmul(e0,m00), g01 = cmul(e0,m01), g10 = cmul(e1,m10), g11 = cmul(e1,m11);
        float* gp = gates + it*8;
        gp[0]=g00.r; gp[1]=g00.i; gp[2]=g01.r; gp[3]=g01.i;
        gp[4]=g10.r; gp[5]=g10.i; gp[6]=g11.r; gp[7]=g11.i;
    }
}

// ---------------- prep2: Wfrag + U frags ----------------
__global__ __launch_bounds__(256) void prep2_kernel(const float* __restrict__ W,
        const float* __restrict__ gates, ushort* __restrict__ wfrag, ushort* __restrict__ ufrag){
    int t = threadIdx.x;
    if (blockIdx.x < 128){
        int tid = blockIdx.x*256 + t;
        int ln = tid & 31, hi = (tid>>5)&1, ds = (tid>>6)&127, ct = tid>>13;
        int n = ct*32 + ln;
        const float* src = W + (size_t)n*2048 + ds*16 + hi*8;
        float4 f0 = *(const float4*)(src);
        float4 f1 = *(const float4*)(src + 4);
        int4 o;
        o.x = (int)pkbf(f0.x, f0.y); o.y = (int)pkbf(f0.z, f0.w);
        o.z = (int)pkbf(f1.x, f1.y); o.w = (int)pkbf(f1.z, f1.w);
        ((int4*)wfrag)[tid] = o;
        return;
    }
    int sh = blockIdx.x - 128;            // set*16 + h
    const float* gp = gates + sh*NQ*8;
    float g[7][8];
    #pragma unroll
    for (int q=0;q<7;++q)
        #pragma unroll
        for (int e=0;e<8;++e) g[q][e] = gp[q*8+e];
    int4* uf = (int4*)ufrag;
    #pragma unroll
    for (int p=0;p<8;++p){
        int pos = t + p*256;
        int ln = pos & 31, hi = (pos>>5)&1, ds = (pos>>6)&7, ct = pos>>9;
        int dp = ct*32 + ln;
        int d0 = ds*16 + hi*8;
        cplx base = {1.f, 0.f};
        #pragma unroll
        for (int q=0;q<4;++q){
            int rb = (dp >> (6-q)) & 1, cb2 = (d0 >> (6-q)) & 1;
            cplx gv = { g[q][rb*4+cb2*2], g[q][rb*4+cb2*2+1] };
            base = cmul(base, gv);
        }
        int r4 = (dp>>2)&1, r5 = (dp>>1)&1, r6 = dp&1;
        float vr[8], vi[8];
        #pragma unroll
        for (int j=0;j<8;++j){
            cplx g4 = { g[4][r4*4 + ((j>>2)&1)*2], g[4][r4*4 + ((j>>2)&1)*2 + 1] };
            cplx g5 = { g[5][r5*4 + ((j>>1)&1)*2], g[5][r5*4 + ((j>>1)&1)*2 + 1] };
            cplx g6 = { g[6][r6*4 + (j&1)*2],      g[6][r6*4 + (j&1)*2 + 1] };
            cplx v = cmul(cmul(cmul(base, g4), g5), g6);
            vr[j] = v.r; vi[j] = v.i;
        }
        int4 outr, outi;
        outr.x = (int)pkbf(vr[0],vr[1]); outr.y = (int)pkbf(vr[2],vr[3]);
        outr.z = (int)pkbf(vr[4],vr[5]); outr.w = (int)pkbf(vr[6],vr[7]);
        outi.x = (int)pkbf(vi[0],vi[1]); outi.y = (int)pkbf(vi[2],vi[3]);
        outi.z = (int)pkbf(vi[4],vi[5]); outi.w = (int)pkbf(vi[6],vi[7]);
        uf[ ((sh*8 + ct)*8 + ds)*64 + hi*32 + ln ]     = outr;
        uf[ ((sh*8 + 4 + ct)*8 + ds)*64 + hi*32 + ln ] = outi;
    }
}

// ---------------- qkv (r9, unchanged) ----------------
__global__ __launch_bounds__(256) void qkv_kernel(const float* __restrict__ states,
        const ushort* __restrict__ ufrag, ushort* __restrict__ qfo,
        ushort* __restrict__ kfo, ushort* __restrict__ vfo){
    __shared__ int xs[128*66];
    int t = threadIdx.x, w = t>>6, lane = t&63, hi = lane>>5, ln = lane&31;
    int blk = blockIdx.x;
    int set = blk >> 9;
    int r9  = blk & 511;
    int bh = r9 >> 4, stile = r9 & 15;
    int b = bh >> 4, h = bh & 15;
    const float sc = 0.12751743f;   // log2(e)/sqrt(128)
    {
        int c = t & 31, tk2 = t >> 5;
        #pragma unroll
        for (int i=0;i<16;++i){
            int tk = i*8 + tk2;
            const float* src = states + ((size_t)(b*SS + stile*128 + tk))*2048 + h*128 + c*4;
            float4 f = *(const float4*)src;
            int2 o; o.x = (int)pkbf(f.x,f.y); o.y = (int)pkbf(f.z,f.w);
            *(int2*)(xs + tk*66 + c*2) = o;
        }
    }
    __syncthreads();
    int ct = w;
    int sh = set*16 + h;
    const int4* ub = (const int4*)ufrag;
    int4* qf4 = (int4*)qfo; int4* kf4 = (int4*)kfo; int4* vf4 = (int4*)vfo;
    bf16x8 ur[8], ui[8];
    #pragma unroll
    for (int ds=0; ds<8; ++ds){
        ur[ds] = *(const bf16x8*)(ub + ((sh*8 + ct)*8 + ds)*64 + lane);
        ui[ds] = *(const bf16x8*)(ub + ((sh*8 + 4 + ct)*8 + ds)*64 + lane);
    }
    #pragma unroll 1
    for (int tt=0; tt<4; ++tt){
        bf16x8 xf[8];
        #pragma unroll
        for (int ds=0; ds<8; ++ds){
            union { bf16x8 v; int2 d[2]; } c;
            const int2* base = (const int2*)(xs + (tt*32 + ln)*66 + ds*8 + hi*4);
            c.d[0] = base[0]; c.d[1] = base[1];
            xf[ds] = c.v;
        }
        f32x16 Cr, Ci;
        #pragma unroll
        for (int r=0;r<16;++r){ Cr[r]=0.f; Ci[r]=0.f; }
        if (set < 2){
            #pragma unroll
            for (int ds=0; ds<8; ++ds){
                Cr = MFMA32(ur[ds], xf[ds], Cr);
                Ci = MFMA32(ui[ds], xf[ds], Ci);
            }
        } else {
            #pragma unroll
            for (int ds=0; ds<8; ++ds){
                Cr = MFMA32(xf[ds], ur[ds], Cr);
                Ci = MFMA32(xf[ds], ui[ds], Ci);
            }
        }
        float pv[16];
        #pragma unroll
        for (int r=0;r<16;++r) pv[r] = Cr[r]*Cr[r] + Ci[r]*Ci[r];
        if (set == 0){
            #pragma unroll
            for (int r=0;r<16;++r) pv[r] *= sc;
        }
        unsigned u2[4][2];
        #pragma unroll
        for (int g2=0; g2<4; ++g2){
            u2[g2][0] = pkbf(pv[g2*4+0], pv[g2*4+1]);
            u2[g2][1] = pkbf(pv[g2*4+2], pv[g2*4+3]);
        }
        int mt = stile*4 + tt;
        #pragma unroll
        for (int gg=0; gg<2; ++gg){
            int g2s = hi*2 + gg, g2p = g2s ^ 2;
            unsigned r0 = (unsigned)__shfl_xor((int)u2[g2p][0], 32);
            unsigned r1 = (unsigned)__shfl_xor((int)u2[g2p][1], 32);
            int4 frag;
            frag.x = (int)(hi ? r0 : u2[g2s][0]);
            frag.y = (int)(hi ? r1 : u2[g2s][1]);
            frag.z = (int)(hi ? u2[g2s][0] : r0);
            frag.w = (int)(hi ? u2[g2s][1] : r1);
            if (set == 0)
                qf4[((bh*64 + mt)*8 + ct*2 + hi)*64 + gg*32 + ln] = frag;
            else if (set == 1)
                kf4[((bh*64 + mt)*8 + ct*2 + hi)*64 + gg*32 + ln] = frag;
            else
                vf4[((bh*4 + ct)*128 + mt*2 + hi)*64 + gg*32 + ln] = frag;
        }
    }
}

// ---------------- flash: 32-key tiles, 32KB dbuf, 3 blocks/CU, XCD swizzle, raw exp2 ----------------
__global__ __launch_bounds__(256, 3) void flash_kernel(const ushort* __restrict__ qfi,
        const ushort* __restrict__ kfi, const ushort* __restrict__ vfi,
        const int* __restrict__ mask, ushort* __restrict__ ctxf){
    __shared__ __align__(16) int4 kbuf[2][512];   // 8 frags x 64 lanes per tile
    __shared__ __align__(16) int4 vbuf[2][512];
    int t = threadIdx.x, w = t>>6, lane = t&63, hi = lane>>5, ln = lane&31;
    // XCD swizzle: slot (bid&7) owns bh in {4k..4k+3} -> K/V set ~4MB per XCD L2
    int bid = blockIdx.x;
    int i2 = bid >> 3;
    int bh = (bid & 7)*4 + (i2 & 3);
    int qt = i2 >> 2;
    int b = bh >> 4;
    const float NEGC = -57.7078018f;   // -40*log2(e); Q carries log2(e) prescale
    const int4* qfp = (const int4*)qfi + (size_t)((bh*64 + qt*4 + w)*8)*64 + lane;
    bf16x8 qf[8];
    #pragma unroll
    for (int ds=0; ds<8; ++ds) qf[ds] = *(const bf16x8*)(qfp + ds*64);
    const int4* kroot = (const int4*)kfi + (size_t)(bh*64)*8*64 + lane;
    const int4* vroot = (const int4*)vfi + (size_t)(bh*4)*128*64 + lane;
    const int* mp = mask + b*SS;
    f32x16 O[4];
    #pragma unroll
    for (int d=0; d<4; ++d){
        #pragma unroll
        for (int r=0;r<16;++r) O[d][r] = 0.f;
    }
    float l0=0.f, l1=0.f, l2=0.f, l3=0.f;
    // stage 32-key tile kt into buffer pb: 8 K frags (waves 0-1) + 8 V frags (waves 2-3)
    auto stage = [&](int kt, int pb){
        if (w < 2){
            int dsb = w*4;
            const int4* src = kroot + ((size_t)kt*8 + dsb)*64;
            int4* dst = &kbuf[pb][dsb*64];
            #pragma unroll
            for (int j=0;j<4;++j) gl_lds16(src + j*64, dst + j*64);
        } else {
            #pragma unroll
            for (int j=0;j<4;++j){
                int v = (w-2)*4 + j;
                int db = v>>1, tt = v&1;
                const int4* src = vroot + ((size_t)db*128 + kt*2 + tt)*64;
                gl_lds16(src, &vbuf[pb][v*64]);
            }
        }
    };
    stage(0, 0);
    for (int kt=0; kt<64; ++kt){
        int p = kt & 1;
        int mk = mp[kt*32 + ln];
        __syncthreads();              // buf[p] ready; buf[p^1] free
        if (kt < 63) stage(kt+1, p^1);
        const int4* kl = kbuf[p];
        const int4* vl = vbuf[p];
        // ---- S^T = K · Q^T (32 keys x 32 q), C-init = NEGC
        f32x16 S;
        #pragma unroll
        for (int r=0;r<16;++r) S[r] = NEGC;
        #pragma unroll
        for (int ds=0; ds<8; ++ds){
            bf16x8 kk = *(const bf16x8*)(kl + ds*64 + lane);
            S = MFMA32(kk, qf[ds], S);
        }
        if (__ballot(mk != 0) != ~0ull){
            #pragma unroll
            for (int r=0;r<16;++r){
                int row0 = ((r>>2)<<3) + (hi<<2) + (r&3);
                if (__shfl(mk, row0) == 0) S[r] = -1e30f;
            }
        }
        // ---- P = 2^S; 4-way split l
        #pragma unroll
        for (int r=0;r<16;++r) S[r] = fexp2(S[r]);
        #pragma unroll
        for (int r=0;r<16;r+=4){
            l0 += S[r]; l1 += S[r+1]; l2 += S[r+2]; l3 += S[r+3];
        }
        // ---- P -> B-frags, PV
        #pragma unroll
        for (int T=0; T<2; ++T){
            unsigned A0 = pkbf(S[8*T+0], S[8*T+1]);
            unsigned A1 = pkbf(S[8*T+2], S[8*T+3]);
            unsigned B0 = pkbf(S[8*T+4], S[8*T+5]);
            unsigned B1 = pkbf(S[8*T+6], S[8*T+7]);
            unsigned X0 = hi ? A0 : B0, X1 = hi ? A1 : B1;
            unsigned Y0 = (unsigned)__shfl_xor((int)X0, 32);
            unsigned Y1 = (unsigned)__shfl_xor((int)X1, 32);
            union { bf16x8 v; unsigned u[4]; } pf;
            pf.u[0] = hi ? Y0 : A0;
            pf.u[1] = hi ? Y1 : A1;
            pf.u[2] = hi ? B0 : Y0;
            pf.u[3] = hi ? B1 : Y1;
            #pragma unroll
            for (int db=0; db<4; ++db){
                bf16x8 vf = *(const bf16x8*)(vl + (db*2 + T)*64 + lane);
                O[db] = MFMA32(vf, pf.v, O[db]);
            }
        }
    }
    float l = (l0+l1) + (l2+l3);
    l += __shfl_xor(l, 32);
    float inv = 1.f / l;
    int h = bh & 15;
    int mt = b*64 + qt*4 + w;
    int4* cf = (int4*)ctxf;
    #pragma unroll
    for (int db=0; db<4; ++db){
        unsigned u[4][2];
        #pragma unroll
        for (int g2=0; g2<4; ++g2){
            u[g2][0] = pkbf(O[db][g2*4+0]*inv, O[db][g2*4+1]*inv);
            u[g2][1] = pkbf(O[db][g2*4+2]*inv, O[db][g2*4+3]*inv);
        }
        #pragma unroll
        for (int gg=0; gg<2; ++gg){
            int g2s = hi*2 + gg;
            int g2p = g2s ^ 2;
            unsigned r0 = (unsigned)__shfl_xor((int)u[g2p][0], 32);
            unsigned r1 = (unsigned)__shfl_xor((int)u[g2p][1], 32);
            int4 frag;
            frag.x = (int)(hi ? r0 : u[g2s][0]);
            frag.y = (int)(hi ? r1 : u[g2s][1]);
            frag.z = (int)(hi ? u[g2s][0] : r0);
            frag.w = (int)(hi ? u[g2s][1] : r1);
            int ds = h*8 + db*2 + hi;
            cf[ ((size_t)(mt*128 + ds)*2 + gg)*32 + ln ] = frag;
        }
    }
}

// ---------------- projection: zero-LDS streaming MFMA ----------------
__global__ __launch_bounds__(256) void proj_kernel(const ushort* __restrict__ ctxf,
                                                   const ushort* __restrict__ wfrag,
                                                   const float* __restrict__ bo,
                                                   float* __restrict__ out){
    int t = threadIdx.x, w = t >> 6, lane = t & 63;
    int hi = lane >> 5, ln = lane & 31;
    int mt = blockIdx.x, ct = w;
    const int4* A = (const int4*)ctxf + (size_t)mt*8192 + lane;
    const int4* B = (const int4*)wfrag + (size_t)ct*8192 + lane;
    f32x16 acc;
    #pragma unroll
    for (int r=0;r<16;++r) acc[r] = 0.f;
    #pragma unroll 8
    for (int ds=0; ds<128; ++ds){
        bf16x8 a = *(const bf16x8*)(A + (size_t)ds*64);
        bf16x8 b = *(const bf16x8*)(B + (size_t)ds*64);
        acc = MFMA32(a, b, acc);
    }
    float bias = bo[ct*32 + ln];
    float* op = out + (size_t)(mt*32)*128 + ct*32 + ln;
    #pragma unroll
    for (int r=0;r<16;++r){
        int row = (r&3) + 8*(r>>2) + 4*hi;
        op[(size_t)row*128] = acc[r] + bias;
    }
}

extern "C" void kernel_launch(void* const* d_in, const int* in_sizes, int n_in,
                              void* d_out, int out_size, void* d_ws, size_t ws_size,
                              hipStream_t stream){
    const float* states = (const float*)d_in[0];
    const int*   mask   = (const int*)d_in[1];
    const float* qp     = (const float*)d_in[2];
    const float* kp     = (const float*)d_in[3];
    const float* vp     = (const float*)d_in[4];
    const float* W      = (const float*)d_in[5];
    const float* bo     = (const float*)d_in[6];
    float* out = (float*)d_out;
    char* wsb = (char*)d_ws;
    float*  gates = (float*) wsb;                              // 16 KB
    ushort* wfrag = (ushort*)(wsb + 16384);                    // 512 KB
    ushort* ufrag = (ushort*)(wsb + 16384 + 524288);           // 3 MB
    char*   big   = wsb + 16384 + 524288 + 3145728;
    ushort* qf    = (ushort*)(big);
    ushort* kf    = (ushort*)(big + 1u*16777216);
    ushort* vf    = (ushort*)(big + 2u*16777216);
    ushort* ctxf  = (ushort*)(big + 3u*16777216);
    hipLaunchKernelGGL(gates_kernel, dim3(1), dim3(256), 0, stream, qp, kp, vp, gates);
    hipLaunchKernelGGL(prep2_kernel, dim3(176), dim3(256), 0, stream, W, gates, wfrag, ufrag);
    hipLaunchKernelGGL(qkv_kernel, dim3(1536), dim3(256), 0, stream, states, ufrag, qf, kf, vf);
    hipLaunchKernelGGL(flash_kernel, dim3(512), dim3(256), 0, stream, qf, kf, vf, mask, ctxf);
    hipLaunchKernelGGL(proj_kernel, dim3(128), dim3(256), 0, stream, ctxf, wfrag, bo, out);
}

// Round 11
// 220.114 us; speedup vs baseline: 1.1978x; 1.1978x over previous
//
#include <hip/hip_runtime.h>
#include <math.h>

#define NH 16
#define DD 128
#define SS 2048
#define NQ 7

typedef __attribute__((ext_vector_type(8))) short bf16x8;
typedef __attribute__((ext_vector_type(16))) float f32x16;

#define MFMA32(a,b,c) __builtin_amdgcn_mfma_f32_32x32x16_bf16(a,b,c,0,0,0)

// manual packed bf16 RNE (HW cvt builtin inflated VGPRs — keep manual)
__device__ __forceinline__ unsigned pkbf(float a, float b){
    unsigned ua = __float_as_uint(a); ua += 0x7FFF + ((ua>>16)&1);
    unsigned ub = __float_as_uint(b); ub += 0x7FFF + ((ub>>16)&1);
    return (ua>>16) | (ub & 0xFFFF0000u);
}

// raw v_exp_f32 (2^x), no libm fixup
__device__ __forceinline__ float fexp2(float x){
#if __has_builtin(__builtin_amdgcn_exp2f)
    return __builtin_amdgcn_exp2f(x);
#else
    return __expf(x * 0.69314718056f);
#endif
}

__device__ __forceinline__ void gl_lds16(const int4* g, int4* l){
    __builtin_amdgcn_global_load_lds((const __attribute__((address_space(1))) void*)g,
                                     (__attribute__((address_space(3))) void*)l, 16, 0, 0);
}

struct cplx { float r, i; };
__device__ __forceinline__ cplx cmul(cplx a, cplx b){ cplx o; o.r = a.r*b.r - a.i*b.i; o.i = a.r*b.i + a.i*b.r; return o; }
__device__ __forceinline__ cplx cadd(cplx a, cplx b){ cplx o; o.r = a.r+b.r; o.i = a.i+b.i; return o; }

// ---------------- gates ----------------
__global__ void gates_kernel(const float* __restrict__ qp, const float* __restrict__ kp,
                             const float* __restrict__ vp, float* __restrict__ gates){
    for (int it = threadIdx.x; it < 3*NH*NQ; it += 256){
        int set = it / (NH*NQ);
        int rem = it % (NH*NQ);
        const float* p = (set==0 ? qp : (set==1 ? kp : vp)) + rem*3;
        float a = p[0]*0.5f, b = p[1]*0.5f, c = p[2]*0.5f;
        float ca=cosf(a), sa=sinf(a), cb=cosf(b), sb=sinf(b), cc=cosf(c), sc=sinf(c);
        cplx rx00={ca,0.f}, rx01={0.f,-sa}, rx10={0.f,-sa}, rx11={ca,0.f};
        cplx ry00={cb,0.f}, ry01={-sb,0.f}, ry10={sb,0.f}, ry11={cb,0.f};
        cplx e0={cc,-sc}, e1={cc,sc};
        cplx m00 = cadd(cmul(ry00,rx00), cmul(ry01,rx10));
        cplx m01 = cadd(cmul(ry00,rx01), cmul(ry01,rx11));
        cplx m10 = cadd(cmul(ry10,rx00), cmul(ry11,rx10));
        cplx m11 = cadd(cmul(ry10,rx01), cmul(ry11,rx11));
        cplx g00 = cmul(e0,m00), g01 = cmul(e0,m01), g10 = cmul(e1,m10), g11 = cmul(e1,m11);
        float* gp = gates + it*8;
        gp[0]=g00.r; gp[1]=g00.i; gp[2]=g01.r; gp[3]=g01.i;
        gp[4]=g10.r; gp[5]=g10.i; gp[6]=g11.r; gp[7]=g11.i;
    }
}

// ---------------- prep2: Wfrag + U frags ----------------
__global__ __launch_bounds__(256) void prep2_kernel(const float* __restrict__ W,
        const float* __restrict__ gates, ushort* __restrict__ wfrag, ushort* __restrict__ ufrag){
    int t = threadIdx.x;
    if (blockIdx.x < 128){
        int tid = blockIdx.x*256 + t;
        int ln = tid & 31, hi = (tid>>5)&1, ds = (tid>>6)&127, ct = tid>>13;
        int n = ct*32 + ln;
        const float* src = W + (size_t)n*2048 + ds*16 + hi*8;
        float4 f0 = *(const float4*)(src);
        float4 f1 = *(const float4*)(src + 4);
        int4 o;
        o.x = (int)pkbf(f0.x, f0.y); o.y = (int)pkbf(f0.z, f0.w);
        o.z = (int)pkbf(f1.x, f1.y); o.w = (int)pkbf(f1.z, f1.w);
        ((int4*)wfrag)[tid] = o;
        return;
    }
    int sh = blockIdx.x - 128;            // set*16 + h
    const float* gp = gates + sh*NQ*8;
    float g[7][8];
    #pragma unroll
    for (int q=0;q<7;++q)
        #pragma unroll
        for (int e=0;e<8;++e) g[q][e] = gp[q*8+e];
    int4* uf = (int4*)ufrag;
    #pragma unroll
    for (int p=0;p<8;++p){
        int pos = t + p*256;
        int ln = pos & 31, hi = (pos>>5)&1, ds = (pos>>6)&7, ct = pos>>9;
        int dp = ct*32 + ln;
        int d0 = ds*16 + hi*8;
        cplx base = {1.f, 0.f};
        #pragma unroll
        for (int q=0;q<4;++q){
            int rb = (dp >> (6-q)) & 1, cb2 = (d0 >> (6-q)) & 1;
            cplx gv = { g[q][rb*4+cb2*2], g[q][rb*4+cb2*2+1] };
            base = cmul(base, gv);
        }
        int r4 = (dp>>2)&1, r5 = (dp>>1)&1, r6 = dp&1;
        float vr[8], vi[8];
        #pragma unroll
        for (int j=0;j<8;++j){
            cplx g4 = { g[4][r4*4 + ((j>>2)&1)*2], g[4][r4*4 + ((j>>2)&1)*2 + 1] };
            cplx g5 = { g[5][r5*4 + ((j>>1)&1)*2], g[5][r5*4 + ((j>>1)&1)*2 + 1] };
            cplx g6 = { g[6][r6*4 + (j&1)*2],      g[6][r6*4 + (j&1)*2 + 1] };
            cplx v = cmul(cmul(cmul(base, g4), g5), g6);
            vr[j] = v.r; vi[j] = v.i;
        }
        int4 outr, outi;
        outr.x = (int)pkbf(vr[0],vr[1]); outr.y = (int)pkbf(vr[2],vr[3]);
        outr.z = (int)pkbf(vr[4],vr[5]); outr.w = (int)pkbf(vr[6],vr[7]);
        outi.x = (int)pkbf(vi[0],vi[1]); outi.y = (int)pkbf(vi[2],vi[3]);
        outi.z = (int)pkbf(vi[4],vi[5]); outi.w = (int)pkbf(vi[6],vi[7]);
        uf[ ((sh*8 + ct)*8 + ds)*64 + hi*32 + ln ]     = outr;
        uf[ ((sh*8 + 4 + ct)*8 + ds)*64 + hi*32 + ln ] = outi;
    }
}

// ---------------- qkv: (256,2) to stop register starvation ----------------
__global__ __launch_bounds__(256, 2) void qkv_kernel(const float* __restrict__ states,
        const ushort* __restrict__ ufrag, ushort* __restrict__ qfo,
        ushort* __restrict__ kfo, ushort* __restrict__ vfo){
    __shared__ int xs[128*66];
    int t = threadIdx.x, w = t>>6, lane = t&63, hi = lane>>5, ln = lane&31;
    int blk = blockIdx.x;
    int set = blk >> 9;
    int r9  = blk & 511;
    int bh = r9 >> 4, stile = r9 & 15;
    int b = bh >> 4, h = bh & 15;
    const float sc = 0.12751743f;   // log2(e)/sqrt(128)
    {
        int c = t & 31, tk2 = t >> 5;
        #pragma unroll
        for (int i=0;i<16;++i){
            int tk = i*8 + tk2;
            const float* src = states + ((size_t)(b*SS + stile*128 + tk))*2048 + h*128 + c*4;
            float4 f = *(const float4*)src;
            int2 o; o.x = (int)pkbf(f.x,f.y); o.y = (int)pkbf(f.z,f.w);
            *(int2*)(xs + tk*66 + c*2) = o;
        }
    }
    __syncthreads();
    int ct = w;
    int sh = set*16 + h;
    const int4* ub = (const int4*)ufrag;
    int4* qf4 = (int4*)qfo; int4* kf4 = (int4*)kfo; int4* vf4 = (int4*)vfo;
    bf16x8 ur[8], ui[8];
    #pragma unroll
    for (int ds=0; ds<8; ++ds){
        ur[ds] = *(const bf16x8*)(ub + ((sh*8 + ct)*8 + ds)*64 + lane);
        ui[ds] = *(const bf16x8*)(ub + ((sh*8 + 4 + ct)*8 + ds)*64 + lane);
    }
    #pragma unroll 1
    for (int tt=0; tt<4; ++tt){
        bf16x8 xf[8];
        #pragma unroll
        for (int ds=0; ds<8; ++ds){
            union { bf16x8 v; int2 d[2]; } c;
            const int2* base = (const int2*)(xs + (tt*32 + ln)*66 + ds*8 + hi*4);
            c.d[0] = base[0]; c.d[1] = base[1];
            xf[ds] = c.v;
        }
        f32x16 Cr, Ci;
        #pragma unroll
        for (int r=0;r<16;++r){ Cr[r]=0.f; Ci[r]=0.f; }
        if (set < 2){
            #pragma unroll
            for (int ds=0; ds<8; ++ds){
                Cr = MFMA32(ur[ds], xf[ds], Cr);
                Ci = MFMA32(ui[ds], xf[ds], Ci);
            }
        } else {
            #pragma unroll
            for (int ds=0; ds<8; ++ds){
                Cr = MFMA32(xf[ds], ur[ds], Cr);
                Ci = MFMA32(xf[ds], ui[ds], Ci);
            }
        }
        float pv[16];
        #pragma unroll
        for (int r=0;r<16;++r) pv[r] = Cr[r]*Cr[r] + Ci[r]*Ci[r];
        if (set == 0){
            #pragma unroll
            for (int r=0;r<16;++r) pv[r] *= sc;
        }
        unsigned u2[4][2];
        #pragma unroll
        for (int g2=0; g2<4; ++g2){
            u2[g2][0] = pkbf(pv[g2*4+0], pv[g2*4+1]);
            u2[g2][1] = pkbf(pv[g2*4+2], pv[g2*4+3]);
        }
        int mt = stile*4 + tt;
        #pragma unroll
        for (int gg=0; gg<2; ++gg){
            int g2s = hi*2 + gg, g2p = g2s ^ 2;
            unsigned r0 = (unsigned)__shfl_xor((int)u2[g2p][0], 32);
            unsigned r1 = (unsigned)__shfl_xor((int)u2[g2p][1], 32);
            int4 frag;
            frag.x = (int)(hi ? r0 : u2[g2s][0]);
            frag.y = (int)(hi ? r1 : u2[g2s][1]);
            frag.z = (int)(hi ? u2[g2s][0] : r0);
            frag.w = (int)(hi ? u2[g2s][1] : r1);
            if (set == 0)
                qf4[((bh*64 + mt)*8 + ct*2 + hi)*64 + gg*32 + ln] = frag;
            else if (set == 1)
                kf4[((bh*64 + mt)*8 + ct*2 + hi)*64 + gg*32 + ln] = frag;
            else
                vf4[((bh*4 + ct)*128 + mt*2 + hi)*64 + gg*32 + ln] = frag;
        }
    }
}

// ---------------- flash: r9 champion verbatim (64-key dbuf, (256,2), XCD swizzle, raw exp) ----------------
__global__ __launch_bounds__(256, 2) void flash_kernel(const ushort* __restrict__ qfi,
        const ushort* __restrict__ kfi, const ushort* __restrict__ vfi,
        const int* __restrict__ mask, ushort* __restrict__ ctxf){
    __shared__ __align__(16) int4 kbuf[2][1024];
    __shared__ __align__(16) int4 vbuf[2][1024];
    int t = threadIdx.x, w = t>>6, lane = t&63, hi = lane>>5, ln = lane&31;
    // XCD swizzle: slot (bid&7) owns bh in {4k..4k+3} -> K/V set ~4MB per XCD L2
    int bid = blockIdx.x;
    int i2 = bid >> 3;
    int bh = (bid & 7)*4 + (i2 & 3);
    int qt = i2 >> 2;
    int b = bh >> 4;
    const float NEGC = -57.7078018f;   // -40*log2(e); Q carries log2(e) prescale
    const int4* qfp = (const int4*)qfi + (size_t)((bh*64 + qt*4 + w)*8)*64 + lane;
    bf16x8 qf[8];
    #pragma unroll
    for (int ds=0; ds<8; ++ds) qf[ds] = *(const bf16x8*)(qfp + ds*64);
    const int4* kg = (const int4*)kfi + (size_t)(bh*64*8)*64 + (w*4)*64 + lane;
    const int4* vg = (const int4*)vfi + ((size_t)(bh*4 + w)*128)*64 + lane;
    const int* mp = mask + b*SS;
    f32x16 O[4];
    #pragma unroll
    for (int d=0; d<4; ++d){
        #pragma unroll
        for (int r=0;r<16;++r) O[d][r] = 0.f;
    }
    float l0=0.f, l1=0.f, l2=0.f, l3=0.f;
    {
        int4* kd = &kbuf[0][(w*4)*64];
        int4* vd = &vbuf[0][(w*4)*64];
        #pragma unroll
        for (int i=0;i<4;++i) gl_lds16(kg + i*64, kd + i*64);
        #pragma unroll
        for (int i=0;i<4;++i) gl_lds16(vg + i*64, vd + i*64);
    }
    for (int kt=0; kt<32; ++kt){
        int p = kt & 1;
        int mk = mp[kt*64 + lane];
        __syncthreads();
        if (kt < 31){
            int4* kd = &kbuf[p^1][(w*4)*64];
            int4* vd = &vbuf[p^1][(w*4)*64];
            const int4* ks = kg + (size_t)(kt+1)*1024;
            const int4* vs = vg + (kt+1)*4*64;
            #pragma unroll
            for (int i=0;i<4;++i) gl_lds16(ks + i*64, kd + i*64);
            #pragma unroll
            for (int i=0;i<4;++i) gl_lds16(vs + i*64, vd + i*64);
        }
        const int4* kl = kbuf[p];
        const int4* vl = vbuf[p];
        f32x16 S0, S1;
        #pragma unroll
        for (int r=0;r<16;++r){ S0[r]=NEGC; S1[r]=NEGC; }
        #pragma unroll
        for (int ds=0; ds<8; ++ds){
            bf16x8 k0 = *(const bf16x8*)(kl + ds*64 + lane);
            bf16x8 k1 = *(const bf16x8*)(kl + (8+ds)*64 + lane);
            S0 = MFMA32(k0, qf[ds], S0);
            S1 = MFMA32(k1, qf[ds], S1);
        }
        if (__ballot(mk != 0) != ~0ull){
            #pragma unroll
            for (int r=0;r<16;++r){
                int row0 = ((r>>2)<<3) + (hi<<2) + (r&3);
                if (__shfl(mk, row0) == 0)      S0[r] = -1e30f;
                if (__shfl(mk, 32 + row0) == 0) S1[r] = -1e30f;
            }
        }
        #pragma unroll
        for (int r=0;r<16;++r){
            S0[r] = fexp2(S0[r]);
            S1[r] = fexp2(S1[r]);
        }
        #pragma unroll
        for (int r=0;r<16;r+=4){
            l0 += S0[r];   l1 += S0[r+1]; l2 += S0[r+2]; l3 += S0[r+3];
            l0 += S1[r];   l1 += S1[r+1]; l2 += S1[r+2]; l3 += S1[r+3];
        }
        #pragma unroll
        for (int m2=0; m2<2; ++m2){
            #pragma unroll
            for (int T=0; T<2; ++T){
                const f32x16& P = m2 ? S1 : S0;
                unsigned A0 = pkbf(P[8*T+0], P[8*T+1]);
                unsigned A1 = pkbf(P[8*T+2], P[8*T+3]);
                unsigned B0 = pkbf(P[8*T+4], P[8*T+5]);
                unsigned B1 = pkbf(P[8*T+6], P[8*T+7]);
                unsigned X0 = hi ? A0 : B0, X1 = hi ? A1 : B1;
                unsigned Y0 = (unsigned)__shfl_xor((int)X0, 32);
                unsigned Y1 = (unsigned)__shfl_xor((int)X1, 32);
                union { bf16x8 v; unsigned u[4]; } pf;
                pf.u[0] = hi ? Y0 : A0;
                pf.u[1] = hi ? Y1 : A1;
                pf.u[2] = hi ? B0 : Y0;
                pf.u[3] = hi ? B1 : Y1;
                int tt = m2*2 + T;
                #pragma unroll
                for (int db=0; db<4; ++db){
                    bf16x8 vf = *(const bf16x8*)(vl + (db*4 + tt)*64 + lane);
                    O[db] = MFMA32(vf, pf.v, O[db]);
                }
            }
        }
    }
    float l = (l0+l1) + (l2+l3);
    l += __shfl_xor(l, 32);
    float inv = 1.f / l;
    int h = bh & 15;
    int mt = b*64 + qt*4 + w;
    int4* cf = (int4*)ctxf;
    #pragma unroll
    for (int db=0; db<4; ++db){
        unsigned u[4][2];
        #pragma unroll
        for (int g2=0; g2<4; ++g2){
            u[g2][0] = pkbf(O[db][g2*4+0]*inv, O[db][g2*4+1]*inv);
            u[g2][1] = pkbf(O[db][g2*4+2]*inv, O[db][g2*4+3]*inv);
        }
        #pragma unroll
        for (int gg=0; gg<2; ++gg){
            int g2s = hi*2 + gg;
            int g2p = g2s ^ 2;
            unsigned r0 = (unsigned)__shfl_xor((int)u[g2p][0], 32);
            unsigned r1 = (unsigned)__shfl_xor((int)u[g2p][1], 32);
            int4 frag;
            frag.x = (int)(hi ? r0 : u[g2s][0]);
            frag.y = (int)(hi ? r1 : u[g2s][1]);
            frag.z = (int)(hi ? u[g2s][0] : r0);
            frag.w = (int)(hi ? u[g2s][1] : r1);
            int ds = h*8 + db*2 + hi;
            cf[ ((size_t)(mt*128 + ds)*2 + gg)*32 + ln ] = frag;
        }
    }
}

// ---------------- projection: K-split, 512 blocks x 2 waves, LDS reduce ----------------
__global__ __launch_bounds__(128) void proj_kernel(const ushort* __restrict__ ctxf,
                                                   const ushort* __restrict__ wfrag,
                                                   const float* __restrict__ bo,
                                                   float* __restrict__ out){
    __shared__ float ls[16][64];
    int t = threadIdx.x, w = t >> 6, lane = t & 63;
    int hi = lane >> 5, ln = lane & 31;
    int mt = blockIdx.x >> 2, ct = blockIdx.x & 3;
    // wave w sums K-half w (64 of 128 ds-steps)
    const int4* A = (const int4*)ctxf + (size_t)mt*8192 + (size_t)w*64*64 + lane;
    const int4* B = (const int4*)wfrag + (size_t)ct*8192 + (size_t)w*64*64 + lane;
    f32x16 acc;
    #pragma unroll
    for (int r=0;r<16;++r) acc[r] = 0.f;
    #pragma unroll 8
    for (int ds=0; ds<64; ++ds){
        bf16x8 a = *(const bf16x8*)(A + (size_t)ds*64);
        bf16x8 b = *(const bf16x8*)(B + (size_t)ds*64);
        acc = MFMA32(a, b, acc);
    }
    if (w == 1){
        #pragma unroll
        for (int r=0;r<16;++r) ls[r][lane] = acc[r];
    }
    __syncthreads();
    if (w == 0){
        float bias = bo[ct*32 + ln];
        float* op = out + (size_t)(mt*32)*128 + ct*32 + ln;
        #pragma unroll
        for (int r=0;r<16;++r){
            int row = (r&3) + 8*(r>>2) + 4*hi;
            op[(size_t)row*128] = acc[r] + ls[r][lane] + bias;
        }
    }
}

extern "C" void kernel_launch(void* const* d_in, const int* in_sizes, int n_in,
                              void* d_out, int out_size, void* d_ws, size_t ws_size,
                              hipStream_t stream){
    const float* states = (const float*)d_in[0];
    const int*   mask   = (const int*)d_in[1];
    const float* qp     = (const float*)d_in[2];
    const float* kp     = (const float*)d_in[3];
    const float* vp     = (const float*)d_in[4];
    const float* W      = (const float*)d_in[5];
    const float* bo     = (const float*)d_in[6];
    float* out = (float*)d_out;
    char* wsb = (char*)d_ws;
    float*  gates = (float*) wsb;                              // 16 KB
    ushort* wfrag = (ushort*)(wsb + 16384);                    // 512 KB
    ushort* ufrag = (ushort*)(wsb + 16384 + 524288);           // 3 MB
    char*   big   = wsb + 16384 + 524288 + 3145728;
    ushort* qf    = (ushort*)(big);
    ushort* kf    = (ushort*)(big + 1u*16777216);
    ushort* vf    = (ushort*)(big + 2u*16777216);
    ushort* ctxf  = (ushort*)(big + 3u*16777216);
    hipLaunchKernelGGL(gates_kernel, dim3(1), dim3(256), 0, stream, qp, kp, vp, gates);
    hipLaunchKernelGGL(prep2_kernel, dim3(176), dim3(256), 0, stream, W, gates, wfrag, ufrag);
    hipLaunchKernelGGL(qkv_kernel, dim3(1536), dim3(256), 0, stream, states, ufrag, qf, kf, vf);
    hipLaunchKernelGGL(flash_kernel, dim3(512), dim3(256), 0, stream, qf, kf, vf, mask, ctxf);
    hipLaunchKernelGGL(proj_kernel, dim3(512), dim3(128), 0, stream, ctxf, wfrag, bo, out);
}

// Round 12
// 218.119 us; speedup vs baseline: 1.2087x; 1.0091x over previous
//
#include <hip/hip_runtime.h>
#include <math.h>

#define NH 16
#define DD 128
#define SS 2048
#define NQ 7

typedef __attribute__((ext_vector_type(8))) short bf16x8;
typedef __attribute__((ext_vector_type(16))) float f32x16;

#define MFMA32(a,b,c) __builtin_amdgcn_mfma_f32_32x32x16_bf16(a,b,c,0,0,0)

// manual packed bf16 RNE (HW cvt builtin inflated VGPRs — keep manual)
__device__ __forceinline__ unsigned pkbf(float a, float b){
    unsigned ua = __float_as_uint(a); ua += 0x7FFF + ((ua>>16)&1);
    unsigned ub = __float_as_uint(b); ub += 0x7FFF + ((ub>>16)&1);
    return (ua>>16) | (ub & 0xFFFF0000u);
}

// raw v_exp_f32 (2^x), no libm fixup
__device__ __forceinline__ float fexp2(float x){
#if __has_builtin(__builtin_amdgcn_exp2f)
    return __builtin_amdgcn_exp2f(x);
#else
    return __expf(x * 0.69314718056f);
#endif
}

__device__ __forceinline__ void gl_lds16(const int4* g, int4* l){
    __builtin_amdgcn_global_load_lds((const __attribute__((address_space(1))) void*)g,
                                     (__attribute__((address_space(3))) void*)l, 16, 0, 0);
}

struct cplx { float r, i; };
__device__ __forceinline__ cplx cmul(cplx a, cplx b){ cplx o; o.r = a.r*b.r - a.i*b.i; o.i = a.r*b.i + a.i*b.r; return o; }
__device__ __forceinline__ cplx cadd(cplx a, cplx b){ cplx o; o.r = a.r+b.r; o.i = a.i+b.i; return o; }

// ---------------- prep2: Wfrag (blocks 0..127) + gates-in-LDS + U frags (128..175) ----------------
__global__ __launch_bounds__(256) void prep2_kernel(const float* __restrict__ qp,
        const float* __restrict__ kp, const float* __restrict__ vp,
        const float* __restrict__ W, ushort* __restrict__ wfrag, ushort* __restrict__ ufrag){
    int t = threadIdx.x;
    if (blockIdx.x < 128){
        int tid = blockIdx.x*256 + t;
        int ln = tid & 31, hi = (tid>>5)&1, ds = (tid>>6)&127, ct = tid>>13;
        int n = ct*32 + ln;
        const float* src = W + (size_t)n*2048 + ds*16 + hi*8;
        float4 f0 = *(const float4*)(src);
        float4 f1 = *(const float4*)(src + 4);
        int4 o;
        o.x = (int)pkbf(f0.x, f0.y); o.y = (int)pkbf(f0.z, f0.w);
        o.z = (int)pkbf(f1.x, f1.y); o.w = (int)pkbf(f1.z, f1.w);
        ((int4*)wfrag)[tid] = o;
        return;
    }
    int sh = blockIdx.x - 128;            // set*16 + h
    __shared__ float gs[7][8];
    if (t < 7){
        int set = sh >> 4, h = sh & 15;
        const float* p = (set==0 ? qp : (set==1 ? kp : vp)) + (h*NQ + t)*3;
        float a = p[0]*0.5f, b = p[1]*0.5f, c = p[2]*0.5f;
        float ca=cosf(a), sa=sinf(a), cb=cosf(b), sb=sinf(b), cc=cosf(c), sc=sinf(c);
        cplx rx00={ca,0.f}, rx01={0.f,-sa}, rx10={0.f,-sa}, rx11={ca,0.f};
        cplx ry00={cb,0.f}, ry01={-sb,0.f}, ry10={sb,0.f}, ry11={cb,0.f};
        cplx e0={cc,-sc}, e1={cc,sc};
        cplx m00 = cadd(cmul(ry00,rx00), cmul(ry01,rx10));
        cplx m01 = cadd(cmul(ry00,rx01), cmul(ry01,rx11));
        cplx m10 = cadd(cmul(ry10,rx00), cmul(ry11,rx10));
        cplx m11 = cadd(cmul(ry10,rx01), cmul(ry11,rx11));
        cplx g00 = cmul(e0,m00), g01 = cmul(e0,m01), g10 = cmul(e1,m10), g11 = cmul(e1,m11);
        gs[t][0]=g00.r; gs[t][1]=g00.i; gs[t][2]=g01.r; gs[t][3]=g01.i;
        gs[t][4]=g10.r; gs[t][5]=g10.i; gs[t][6]=g11.r; gs[t][7]=g11.i;
    }
    __syncthreads();
    float g[7][8];
    #pragma unroll
    for (int q=0;q<7;++q)
        #pragma unroll
        for (int e=0;e<8;++e) g[q][e] = gs[q][e];
    int4* uf = (int4*)ufrag;
    #pragma unroll
    for (int p=0;p<8;++p){
        int pos = t + p*256;
        int ln = pos & 31, hi = (pos>>5)&1, ds = (pos>>6)&7, ct = pos>>9;
        int dp = ct*32 + ln;
        int d0 = ds*16 + hi*8;
        cplx base = {1.f, 0.f};
        #pragma unroll
        for (int q=0;q<4;++q){
            int rb = (dp >> (6-q)) & 1, cb2 = (d0 >> (6-q)) & 1;
            cplx gv = { g[q][rb*4+cb2*2], g[q][rb*4+cb2*2+1] };
            base = cmul(base, gv);
        }
        int r4 = (dp>>2)&1, r5 = (dp>>1)&1, r6 = dp&1;
        float vr[8], vi[8];
        #pragma unroll
        for (int j=0;j<8;++j){
            cplx g4 = { g[4][r4*4 + ((j>>2)&1)*2], g[4][r4*4 + ((j>>2)&1)*2 + 1] };
            cplx g5 = { g[5][r5*4 + ((j>>1)&1)*2], g[5][r5*4 + ((j>>1)&1)*2 + 1] };
            cplx g6 = { g[6][r6*4 + (j&1)*2],      g[6][r6*4 + (j&1)*2 + 1] };
            cplx v = cmul(cmul(cmul(base, g4), g5), g6);
            vr[j] = v.r; vi[j] = v.i;
        }
        int4 outr, outi;
        outr.x = (int)pkbf(vr[0],vr[1]); outr.y = (int)pkbf(vr[2],vr[3]);
        outr.z = (int)pkbf(vr[4],vr[5]); outr.w = (int)pkbf(vr[6],vr[7]);
        outi.x = (int)pkbf(vi[0],vi[1]); outi.y = (int)pkbf(vi[2],vi[3]);
        outi.z = (int)pkbf(vi[4],vi[5]); outi.w = (int)pkbf(vi[6],vi[7]);
        uf[ ((sh*8 + ct)*8 + ds)*64 + hi*32 + ln ]     = outr;
        uf[ ((sh*8 + 4 + ct)*8 + ds)*64 + hi*32 + ln ] = outi;
    }
}

// ---------------- qkv: 3072 blocks (set, bh, 64-token stile); wave = ct, 2 token-tiles ----------------
__global__ __launch_bounds__(256, 2) void qkv_kernel(const float* __restrict__ states,
        const ushort* __restrict__ ufrag, ushort* __restrict__ qfo,
        ushort* __restrict__ kfo, ushort* __restrict__ vfo){
    __shared__ int xs[64*66];      // 64 tokens x 132 bf16 (2-way-only conflicts: free)
    int t = threadIdx.x, w = t>>6, lane = t&63, hi = lane>>5, ln = lane&31;
    int blk = blockIdx.x;
    int set = blk >> 10;           // 0..2
    int r10 = blk & 1023;
    int bh = r10 >> 5, stile = r10 & 31;   // stile: 64-token tile
    int b = bh >> 4, h = bh & 15;
    const float sc = 0.12751743f;  // log2(e)/sqrt(128): softmax uses exp2
    // ---- stage X: 8 passes, 8 tokens/pass, per-token 512B by 32 lanes (coalesced)
    {
        int c = t & 31, tk2 = t >> 5;
        #pragma unroll
        for (int i=0;i<8;++i){
            int tk = i*8 + tk2;
            const float* src = states + ((size_t)(b*SS + stile*64 + tk))*2048 + h*128 + c*4;
            float4 f = *(const float4*)src;
            int2 o; o.x = (int)pkbf(f.x,f.y); o.y = (int)pkbf(f.z,f.w);
            *(int2*)(xs + tk*66 + c*2) = o;
        }
    }
    __syncthreads();
    int ct = w;
    int sh = set*16 + h;
    const int4* ub = (const int4*)ufrag;
    int4* qf4 = (int4*)qfo; int4* kf4 = (int4*)kfo; int4* vf4 = (int4*)vfo;
    bf16x8 ur[8], ui[8];
    #pragma unroll
    for (int ds=0; ds<8; ++ds){
        ur[ds] = *(const bf16x8*)(ub + ((sh*8 + ct)*8 + ds)*64 + lane);
        ui[ds] = *(const bf16x8*)(ub + ((sh*8 + 4 + ct)*8 + ds)*64 + lane);
    }
    #pragma unroll 1
    for (int tt=0; tt<2; ++tt){
        bf16x8 xf[8];
        #pragma unroll
        for (int ds=0; ds<8; ++ds){
            union { bf16x8 v; int2 d[2]; } c;
            const int2* base = (const int2*)(xs + (tt*32 + ln)*66 + ds*8 + hi*4);
            c.d[0] = base[0]; c.d[1] = base[1];
            xf[ds] = c.v;
        }
        f32x16 Cr, Ci;
        #pragma unroll
        for (int r=0;r<16;++r){ Cr[r]=0.f; Ci[r]=0.f; }
        if (set < 2){
            #pragma unroll
            for (int ds=0; ds<8; ++ds){
                Cr = MFMA32(ur[ds], xf[ds], Cr);
                Ci = MFMA32(ui[ds], xf[ds], Ci);
            }
        } else {
            #pragma unroll
            for (int ds=0; ds<8; ++ds){
                Cr = MFMA32(xf[ds], ur[ds], Cr);
                Ci = MFMA32(xf[ds], ui[ds], Ci);
            }
        }
        float pv[16];
        #pragma unroll
        for (int r=0;r<16;++r) pv[r] = Cr[r]*Cr[r] + Ci[r]*Ci[r];
        if (set == 0){
            #pragma unroll
            for (int r=0;r<16;++r) pv[r] *= sc;
        }
        unsigned u2[4][2];
        #pragma unroll
        for (int g2=0; g2<4; ++g2){
            u2[g2][0] = pkbf(pv[g2*4+0], pv[g2*4+1]);
            u2[g2][1] = pkbf(pv[g2*4+2], pv[g2*4+3]);
        }
        int mt = stile*2 + tt;
        #pragma unroll
        for (int gg=0; gg<2; ++gg){
            int g2s = hi*2 + gg, g2p = g2s ^ 2;
            unsigned r0 = (unsigned)__shfl_xor((int)u2[g2p][0], 32);
            unsigned r1 = (unsigned)__shfl_xor((int)u2[g2p][1], 32);
            int4 frag;
            frag.x = (int)(hi ? r0 : u2[g2s][0]);
            frag.y = (int)(hi ? r1 : u2[g2s][1]);
            frag.z = (int)(hi ? u2[g2s][0] : r0);
            frag.w = (int)(hi ? u2[g2s][1] : r1);
            if (set == 0)
                qf4[((bh*64 + mt)*8 + ct*2 + hi)*64 + gg*32 + ln] = frag;
            else if (set == 1)
                kf4[((bh*64 + mt)*8 + ct*2 + hi)*64 + gg*32 + ln] = frag;
            else
                vf4[((bh*4 + ct)*128 + mt*2 + hi)*64 + gg*32 + ln] = frag;
        }
    }
}

// ---------------- flash: r9/r11 champion verbatim ----------------
__global__ __launch_bounds__(256, 2) void flash_kernel(const ushort* __restrict__ qfi,
        const ushort* __restrict__ kfi, const ushort* __restrict__ vfi,
        const int* __restrict__ mask, ushort* __restrict__ ctxf){
    __shared__ __align__(16) int4 kbuf[2][1024];
    __shared__ __align__(16) int4 vbuf[2][1024];
    int t = threadIdx.x, w = t>>6, lane = t&63, hi = lane>>5, ln = lane&31;
    int bid = blockIdx.x;
    int i2 = bid >> 3;
    int bh = (bid & 7)*4 + (i2 & 3);
    int qt = i2 >> 2;
    int b = bh >> 4;
    const float NEGC = -57.7078018f;   // -40*log2(e); Q carries log2(e) prescale
    const int4* qfp = (const int4*)qfi + (size_t)((bh*64 + qt*4 + w)*8)*64 + lane;
    bf16x8 qf[8];
    #pragma unroll
    for (int ds=0; ds<8; ++ds) qf[ds] = *(const bf16x8*)(qfp + ds*64);
    const int4* kg = (const int4*)kfi + (size_t)(bh*64*8)*64 + (w*4)*64 + lane;
    const int4* vg = (const int4*)vfi + ((size_t)(bh*4 + w)*128)*64 + lane;
    const int* mp = mask + b*SS;
    f32x16 O[4];
    #pragma unroll
    for (int d=0; d<4; ++d){
        #pragma unroll
        for (int r=0;r<16;++r) O[d][r] = 0.f;
    }
    float l0=0.f, l1=0.f, l2=0.f, l3=0.f;
    {
        int4* kd = &kbuf[0][(w*4)*64];
        int4* vd = &vbuf[0][(w*4)*64];
        #pragma unroll
        for (int i=0;i<4;++i) gl_lds16(kg + i*64, kd + i*64);
        #pragma unroll
        for (int i=0;i<4;++i) gl_lds16(vg + i*64, vd + i*64);
    }
    for (int kt=0; kt<32; ++kt){
        int p = kt & 1;
        int mk = mp[kt*64 + lane];
        __syncthreads();
        if (kt < 31){
            int4* kd = &kbuf[p^1][(w*4)*64];
            int4* vd = &vbuf[p^1][(w*4)*64];
            const int4* ks = kg + (size_t)(kt+1)*1024;
            const int4* vs = vg + (kt+1)*4*64;
            #pragma unroll
            for (int i=0;i<4;++i) gl_lds16(ks + i*64, kd + i*64);
            #pragma unroll
            for (int i=0;i<4;++i) gl_lds16(vs + i*64, vd + i*64);
        }
        const int4* kl = kbuf[p];
        const int4* vl = vbuf[p];
        f32x16 S0, S1;
        #pragma unroll
        for (int r=0;r<16;++r){ S0[r]=NEGC; S1[r]=NEGC; }
        #pragma unroll
        for (int ds=0; ds<8; ++ds){
            bf16x8 k0 = *(const bf16x8*)(kl + ds*64 + lane);
            bf16x8 k1 = *(const bf16x8*)(kl + (8+ds)*64 + lane);
            S0 = MFMA32(k0, qf[ds], S0);
            S1 = MFMA32(k1, qf[ds], S1);
        }
        if (__ballot(mk != 0) != ~0ull){
            #pragma unroll
            for (int r=0;r<16;++r){
                int row0 = ((r>>2)<<3) + (hi<<2) + (r&3);
                if (__shfl(mk, row0) == 0)      S0[r] = -1e30f;
                if (__shfl(mk, 32 + row0) == 0) S1[r] = -1e30f;
            }
        }
        #pragma unroll
        for (int r=0;r<16;++r){
            S0[r] = fexp2(S0[r]);
            S1[r] = fexp2(S1[r]);
        }
        #pragma unroll
        for (int r=0;r<16;r+=4){
            l0 += S0[r];   l1 += S0[r+1]; l2 += S0[r+2]; l3 += S0[r+3];
            l0 += S1[r];   l1 += S1[r+1]; l2 += S1[r+2]; l3 += S1[r+3];
        }
        #pragma unroll
        for (int m2=0; m2<2; ++m2){
            #pragma unroll
            for (int T=0; T<2; ++T){
                const f32x16& P = m2 ? S1 : S0;
                unsigned A0 = pkbf(P[8*T+0], P[8*T+1]);
                unsigned A1 = pkbf(P[8*T+2], P[8*T+3]);
                unsigned B0 = pkbf(P[8*T+4], P[8*T+5]);
                unsigned B1 = pkbf(P[8*T+6], P[8*T+7]);
                unsigned X0 = hi ? A0 : B0, X1 = hi ? A1 : B1;
                unsigned Y0 = (unsigned)__shfl_xor((int)X0, 32);
                unsigned Y1 = (unsigned)__shfl_xor((int)X1, 32);
                union { bf16x8 v; unsigned u[4]; } pf;
                pf.u[0] = hi ? Y0 : A0;
                pf.u[1] = hi ? Y1 : A1;
                pf.u[2] = hi ? B0 : Y0;
                pf.u[3] = hi ? B1 : Y1;
                int tt = m2*2 + T;
                #pragma unroll
                for (int db=0; db<4; ++db){
                    bf16x8 vf = *(const bf16x8*)(vl + (db*4 + tt)*64 + lane);
                    O[db] = MFMA32(vf, pf.v, O[db]);
                }
            }
        }
    }
    float l = (l0+l1) + (l2+l3);
    l += __shfl_xor(l, 32);
    float inv = 1.f / l;
    int h = bh & 15;
    int mt = b*64 + qt*4 + w;
    int4* cf = (int4*)ctxf;
    #pragma unroll
    for (int db=0; db<4; ++db){
        unsigned u[4][2];
        #pragma unroll
        for (int g2=0; g2<4; ++g2){
            u[g2][0] = pkbf(O[db][g2*4+0]*inv, O[db][g2*4+1]*inv);
            u[g2][1] = pkbf(O[db][g2*4+2]*inv, O[db][g2*4+3]*inv);
        }
        #pragma unroll
        for (int gg=0; gg<2; ++gg){
            int g2s = hi*2 + gg;
            int g2p = g2s ^ 2;
            unsigned r0 = (unsigned)__shfl_xor((int)u[g2p][0], 32);
            unsigned r1 = (unsigned)__shfl_xor((int)u[g2p][1], 32);
            int4 frag;
            frag.x = (int)(hi ? r0 : u[g2s][0]);
            frag.y = (int)(hi ? r1 : u[g2s][1]);
            frag.z = (int)(hi ? u[g2s][0] : r0);
            frag.w = (int)(hi ? u[g2s][1] : r1);
            int ds = h*8 + db*2 + hi;
            cf[ ((size_t)(mt*128 + ds)*2 + gg)*32 + ln ] = frag;
        }
    }
}

// ---------------- projection: 4-way K-split, 256 threads, LDS reduce ----------------
__global__ __launch_bounds__(256) void proj_kernel(const ushort* __restrict__ ctxf,
                                                   const ushort* __restrict__ wfrag,
                                                   const float* __restrict__ bo,
                                                   float* __restrict__ out){
    __shared__ float ls[3][16][64];
    int t = threadIdx.x, w = t >> 6, lane = t & 63;
    int hi = lane >> 5, ln = lane & 31;
    int mt = blockIdx.x >> 2, ct = blockIdx.x & 3;
    // wave w sums K-quarter w (32 of 128 ds-steps)
    const int4* A = (const int4*)ctxf + (size_t)mt*8192 + (size_t)w*32*64 + lane;
    const int4* B = (const int4*)wfrag + (size_t)ct*8192 + (size_t)w*32*64 + lane;
    f32x16 acc;
    #pragma unroll
    for (int r=0;r<16;++r) acc[r] = 0.f;
    #pragma unroll 8
    for (int ds=0; ds<32; ++ds){
        bf16x8 a = *(const bf16x8*)(A + (size_t)ds*64);
        bf16x8 b = *(const bf16x8*)(B + (size_t)ds*64);
        acc = MFMA32(a, b, acc);
    }
    if (w > 0){
        #pragma unroll
        for (int r=0;r<16;++r) ls[w-1][r][lane] = acc[r];
    }
    __syncthreads();
    if (w == 0){
        float bias = bo[ct*32 + ln];
        float* op = out + (size_t)(mt*32)*128 + ct*32 + ln;
        #pragma unroll
        for (int r=0;r<16;++r){
            int row = (r&3) + 8*(r>>2) + 4*hi;
            float s = acc[r] + ls[0][r][lane] + ls[1][r][lane] + ls[2][r][lane] + bias;
            op[(size_t)row*128] = s;
        }
    }
}

extern "C" void kernel_launch(void* const* d_in, const int* in_sizes, int n_in,
                              void* d_out, int out_size, void* d_ws, size_t ws_size,
                              hipStream_t stream){
    const float* states = (const float*)d_in[0];
    const int*   mask   = (const int*)d_in[1];
    const float* qp     = (const float*)d_in[2];
    const float* kp     = (const float*)d_in[3];
    const float* vp     = (const float*)d_in[4];
    const float* W      = (const float*)d_in[5];
    const float* bo     = (const float*)d_in[6];
    float* out = (float*)d_out;
    char* wsb = (char*)d_ws;
    ushort* wfrag = (ushort*)(wsb + 16384);                    // 512 KB
    ushort* ufrag = (ushort*)(wsb + 16384 + 524288);           // 3 MB
    char*   big   = wsb + 16384 + 524288 + 3145728;
    ushort* qf    = (ushort*)(big);
    ushort* kf    = (ushort*)(big + 1u*16777216);
    ushort* vf    = (ushort*)(big + 2u*16777216);
    ushort* ctxf  = (ushort*)(big + 3u*16777216);
    hipLaunchKernelGGL(prep2_kernel, dim3(176), dim3(256), 0, stream, qp, kp, vp, W, wfrag, ufrag);
    hipLaunchKernelGGL(qkv_kernel, dim3(3072), dim3(256), 0, stream, states, ufrag, qf, kf, vf);
    hipLaunchKernelGGL(flash_kernel, dim3(512), dim3(256), 0, stream, qf, kf, vf, mask, ctxf);
    hipLaunchKernelGGL(proj_kernel, dim3(512), dim3(256), 0, stream, ctxf, wfrag, bo, out);
}